// Round 2
// baseline (695.128 us; speedup 1.0000x reference)
//
#include <hip/hip_runtime.h>
#include <cstdint>
#include <cstddef>

#define M_DIM 8192
#define N_DIM 4096
#define K_DIM 4096

typedef __attribute__((ext_vector_type(8))) short bf16x8;
typedef __attribute__((ext_vector_type(4))) float floatx4;

__device__ __forceinline__ ushort f2bf_rne(float f) {
    union { float f; uint32_t u; } a;
    a.f = f;
    uint32_t u = a.u;
    uint32_t r = (u + 0x7fffu + ((u >> 16) & 1u)) >> 16;
    return (ushort)r;
}

// ---------------------------------------------------------------------------
// Kernel 1: packed int4 (one signed byte per int32) -> dequant -> bf16 (RNE)
// flat nibble index f = 2*p (+1 for high); row o = f/4096; group g = o/128
// => g = p >> 18 (uniform across an aligned int4 of 4 packed bytes)
// WS usage: N*K*2 = 33,554,432 bytes ONLY (round-1 used 100.7MB and overran
// d_ws, corrupting the harness's pristine buffers -> post-timing divergence).
// ---------------------------------------------------------------------------
__global__ void dequant_w_kernel(const int4* __restrict__ pw,
                                 const float* __restrict__ scales,
                                 const float* __restrict__ zps,
                                 uint4* __restrict__ wb, int np4) {
    int p4 = blockIdx.x * blockDim.x + threadIdx.x;
    if (p4 >= np4) return;
    int p = p4 * 4;            // int32 (byte) index
    int g = p >> 18;           // group, uniform over the 8 nibbles here
    float s = scales[g];
    float b = -zps[g] * s;
    int4 v = pw[p4];
    int vv[4] = { v.x, v.y, v.z, v.w };
    ushort o[8];
#pragma unroll
    for (int j = 0; j < 4; ++j) {
        int lo = ((int)((uint32_t)vv[j] << 28)) >> 28;
        int hi = ((int)((uint32_t)vv[j] << 24)) >> 28;
        o[2 * j]     = f2bf_rne(fmaf((float)lo, s, b));
        o[2 * j + 1] = f2bf_rne(fmaf((float)hi, s, b));
    }
    uint4 st;
    st.x = (uint32_t)o[0] | ((uint32_t)o[1] << 16);
    st.y = (uint32_t)o[2] | ((uint32_t)o[3] << 16);
    st.z = (uint32_t)o[4] | ((uint32_t)o[5] << 16);
    st.w = (uint32_t)o[6] | ((uint32_t)o[7] << 16);
    wb[p4] = st;
}

// ---------------------------------------------------------------------------
// Kernel 2: GEMM with fused fp32->bf16 conversion of A (x) at staging time.
// A = x [M][K] fp32, B = W_bf16 [N][K] (K-contiguous), C = A*B^T + bias.
// 128x128 tile, BK=32, 4 waves, each 64x64 via 4x4 mfma_f32_16x16x32_bf16.
// A: global fp32 loads -> v_perm truncate-pack -> ds_write_b128 (bf16 LDS).
// B: async global_load_lds width=16 (m97 path).
// ---------------------------------------------------------------------------
#define BM 128
#define BN 128
#define BK 32

// pack two fp32 into two bf16 (truncation): bytes [f0.b2,f0.b3,f1.b2,f1.b3]
__device__ __forceinline__ uint32_t pk_bf_trunc(float f0, float f1) {
    return __builtin_amdgcn_perm(__float_as_uint(f1), __float_as_uint(f0),
                                 0x07060302u);
}

__global__ void gemm_fa_kernel(const float* __restrict__ X,
                               const ushort* __restrict__ B,
                               const float* __restrict__ bias,
                               float* __restrict__ C) {
    __shared__ ushort As[BM * BK];  // 8 KB bf16
    __shared__ ushort Bs[BN * BK];  // 8 KB bf16

    const int tid  = threadIdx.x;
    const int lane = tid & 63;
    const int wave = tid >> 6;       // 0..3
    const int wm   = wave >> 1;
    const int wn   = wave & 1;
    const int bm   = blockIdx.y;     // M block (64)
    const int bn   = blockIdx.x;     // N block (32)

    // A staging: thread t handles row (t>>1), k-cols (t&1)*16 .. +16
    const int ar  = tid >> 1;
    const int ac0 = (tid & 1) * 16;
    const float* xp = X + (size_t)(bm * BM + ar) * K_DIM + ac0;
    ushort* asd = As + ar * BK + ac0;

    // B staging: chunk = wave*2+q covers 16 rows (row = 32 bf16 = 64B);
    // lane covers row chunk*16 + (lane>>2), cols (lane&3)*8 .. +8 (16B)
    const int scol = (lane & 3) * 8;
    const ushort* Bb = B + (size_t)(bn * BN) * K_DIM;

    floatx4 acc[4][4] = {};

    for (int k0 = 0; k0 < K_DIM; k0 += BK) {
        // ---- A global loads (fp32) ----
        float4 v0 = *(const float4*)(xp + k0);
        float4 v1 = *(const float4*)(xp + k0 + 4);
        float4 v2 = *(const float4*)(xp + k0 + 8);
        float4 v3 = *(const float4*)(xp + k0 + 12);
        // ---- B async global -> LDS ----
#pragma unroll
        for (int q = 0; q < 2; ++q) {
            const int chunk = wave * 2 + q;
            const int r = chunk * 16 + (lane >> 2);
            const ushort* gb = Bb + (size_t)r * K_DIM + k0 + scol;
            __builtin_amdgcn_global_load_lds(
                (const __attribute__((address_space(1))) void*)gb,
                (__attribute__((address_space(3))) void*)(Bs + chunk * 512),
                16, 0, 0);
        }
        // ---- convert A to bf16 (truncate) and write to LDS ----
        uint4 w0, w1;
        w0.x = pk_bf_trunc(v0.x, v0.y);
        w0.y = pk_bf_trunc(v0.z, v0.w);
        w0.z = pk_bf_trunc(v1.x, v1.y);
        w0.w = pk_bf_trunc(v1.z, v1.w);
        w1.x = pk_bf_trunc(v2.x, v2.y);
        w1.y = pk_bf_trunc(v2.z, v2.w);
        w1.z = pk_bf_trunc(v3.x, v3.y);
        w1.w = pk_bf_trunc(v3.z, v3.w);
        *(uint4*)asd       = w0;
        *(uint4*)(asd + 8) = w1;

        __syncthreads();   // drains vmcnt+lgkmcnt before barrier

        // fragment loads: operand elem j of lane l is T[row=l&15][k=(l>>4)*8+j]
        bf16x8 af[4], bfr[4];
        const int frow = lane & 15;
        const int fcol = (lane >> 4) * 8;
#pragma unroll
        for (int i = 0; i < 4; ++i) {
            af[i]  = *(const bf16x8*)(As + (wm * 64 + i * 16 + frow) * BK + fcol);
            bfr[i] = *(const bf16x8*)(Bs + (wn * 64 + i * 16 + frow) * BK + fcol);
        }
#pragma unroll
        for (int i = 0; i < 4; ++i)
#pragma unroll
            for (int j = 0; j < 4; ++j)
                acc[i][j] = __builtin_amdgcn_mfma_f32_16x16x32_bf16(
                    af[i], bfr[j], acc[i][j], 0, 0, 0);
        __syncthreads();
    }

    // epilogue: C/D layout col=lane&15, row=(lane>>4)*4+reg
    const int crow0 = bm * BM + wm * 64;
    const int ccol0 = bn * BN + wn * 64;
    const int rl = lane >> 4;
    const int cl = lane & 15;
#pragma unroll
    for (int j = 0; j < 4; ++j) {
        const int col = ccol0 + j * 16 + cl;
        const float bv = bias[col];
#pragma unroll
        for (int i = 0; i < 4; ++i) {
            const int row = crow0 + i * 16 + rl * 4;
            float* cp = C + (size_t)row * N_DIM + col;
#pragma unroll
            for (int r = 0; r < 4; ++r)
                cp[(size_t)r * N_DIM] = acc[i][j][r] + bv;
        }
    }
}

// ---------------------------------------------------------------------------
extern "C" void kernel_launch(void* const* d_in, const int* in_sizes, int n_in,
                              void* d_out, int out_size, void* d_ws, size_t ws_size,
                              hipStream_t stream) {
    const float* x      = (const float*)d_in[0];
    const int*   pw     = (const int*)d_in[1];
    const float* scales = (const float*)d_in[2];
    const float* zps    = (const float*)d_in[3];
    const float* bias   = (const float*)d_in[4];
    float* out = (float*)d_out;

    // workspace: ONLY W_bf16 [N*K] ushort = 33,554,432 bytes
    ushort* wb = (ushort*)d_ws;

    {
        int np4 = (N_DIM * K_DIM / 2) / 4;  // 2,097,152
        dequant_w_kernel<<<np4 / 256, 256, 0, stream>>>(
            (const int4*)pw, scales, zps, (uint4*)wb, np4);
    }
    {
        dim3 grid(N_DIM / BN, M_DIM / BM);  // (32, 64)
        gemm_fa_kernel<<<grid, 256, 0, stream>>>(x, wb, bias, out);
    }
}

// Round 3
// 553.157 us; speedup vs baseline: 1.2567x; 1.2567x over previous
//
#include <hip/hip_runtime.h>
#include <cstdint>
#include <cstddef>

#define M_DIM 8192
#define N_DIM 4096
#define K_DIM 4096
#define CHUNK_M 4096   // x converted in 2 chunks of 33.5 MB so ws stays <= 67.1 MB

typedef __attribute__((ext_vector_type(8))) short bf16x8;
typedef __attribute__((ext_vector_type(4))) float floatx4;

__device__ __forceinline__ ushort f2bf_rne(float f) {
    union { float f; uint32_t u; } a;
    a.f = f;
    uint32_t u = a.u;
    uint32_t r = (u + 0x7fffu + ((u >> 16) & 1u)) >> 16;
    return (ushort)r;
}

// pack two fp32 into two bf16 (truncation), 1 instr
__device__ __forceinline__ uint32_t pk_bf_trunc(float f0, float f1) {
    return __builtin_amdgcn_perm(__float_as_uint(f1), __float_as_uint(f0),
                                 0x07060302u);
}

// ---------------------------------------------------------------------------
// Kernel 1: packed int4 (one signed byte per int32) -> dequant -> bf16 (RNE)
// group g = p>>18 is uniform across each aligned int4 of packed bytes.
// ---------------------------------------------------------------------------
__global__ void dequant_w_kernel(const int4* __restrict__ pw,
                                 const float* __restrict__ scales,
                                 const float* __restrict__ zps,
                                 uint4* __restrict__ wb, int np4) {
    int p4 = blockIdx.x * blockDim.x + threadIdx.x;
    if (p4 >= np4) return;
    int p = p4 * 4;
    int g = p >> 18;
    float s = scales[g];
    float b = -zps[g] * s;
    int4 v = pw[p4];
    int vv[4] = { v.x, v.y, v.z, v.w };
    ushort o[8];
#pragma unroll
    for (int j = 0; j < 4; ++j) {
        int lo = ((int)((uint32_t)vv[j] << 28)) >> 28;
        int hi = ((int)((uint32_t)vv[j] << 24)) >> 28;
        o[2 * j]     = f2bf_rne(fmaf((float)lo, s, b));
        o[2 * j + 1] = f2bf_rne(fmaf((float)hi, s, b));
    }
    uint4 st;
    st.x = (uint32_t)o[0] | ((uint32_t)o[1] << 16);
    st.y = (uint32_t)o[2] | ((uint32_t)o[3] << 16);
    st.z = (uint32_t)o[4] | ((uint32_t)o[5] << 16);
    st.w = (uint32_t)o[6] | ((uint32_t)o[7] << 16);
    wb[p4] = st;
}

// ---------------------------------------------------------------------------
// Kernel 2: x fp32 -> bf16 (RNE), one chunk of CHUNK_M rows
// ---------------------------------------------------------------------------
__global__ void convert_x_kernel(const float4* __restrict__ x4,
                                 ushort4* __restrict__ out4, int n4) {
    int i = blockIdx.x * blockDim.x + threadIdx.x;
    if (i >= n4) return;
    float4 v = x4[i];
    ushort4 o;
    o.x = f2bf_rne(v.x);
    o.y = f2bf_rne(v.y);
    o.z = f2bf_rne(v.z);
    o.w = f2bf_rne(v.w);
    out4[i] = o;
}

// ---------------------------------------------------------------------------
// Kernel 3a: pure-bf16 GEMM, exact m97 structure (A and B both via
// global_load_lds width=16 — conflict-free LDS writes by construction).
// A [Mc][K] bf16 row-major, B [N][K] bf16 row-major. C = A*B^T + bias.
// 128x128 tile, BK=32, 4 waves, 4x4 mfma_f32_16x16x32_bf16 each.
// ---------------------------------------------------------------------------
#define BM 128
#define BN 128
#define BK 32

__global__ void gemm_bf16_kernel(const ushort* __restrict__ A,
                                 const ushort* __restrict__ B,
                                 const float* __restrict__ bias,
                                 float* __restrict__ C) {
    __shared__ ushort As[BM * BK];
    __shared__ ushort Bs[BN * BK];

    const int tid  = threadIdx.x;
    const int lane = tid & 63;
    const int wave = tid >> 6;
    const int wm   = wave >> 1;
    const int wn   = wave & 1;
    const int bm   = blockIdx.y;
    const int bn   = blockIdx.x;

    const int scol = (lane & 3) * 8;
    const ushort* Ab = A + (size_t)(bm * BM) * K_DIM;
    const ushort* Bb = B + (size_t)(bn * BN) * K_DIM;

    floatx4 acc[4][4] = {};

    for (int k0 = 0; k0 < K_DIM; k0 += BK) {
#pragma unroll
        for (int q = 0; q < 2; ++q) {
            const int chunk = wave * 2 + q;
            const int r = chunk * 16 + (lane >> 2);
            const ushort* ga = Ab + (size_t)r * K_DIM + k0 + scol;
            const ushort* gb = Bb + (size_t)r * K_DIM + k0 + scol;
            __builtin_amdgcn_global_load_lds(
                (const __attribute__((address_space(1))) void*)ga,
                (__attribute__((address_space(3))) void*)(As + chunk * 512),
                16, 0, 0);
            __builtin_amdgcn_global_load_lds(
                (const __attribute__((address_space(1))) void*)gb,
                (__attribute__((address_space(3))) void*)(Bs + chunk * 512),
                16, 0, 0);
        }
        __syncthreads();

        bf16x8 af[4], bfr[4];
        const int frow = lane & 15;
        const int fcol = (lane >> 4) * 8;
#pragma unroll
        for (int i = 0; i < 4; ++i) {
            af[i]  = *(const bf16x8*)(As + (wm * 64 + i * 16 + frow) * BK + fcol);
            bfr[i] = *(const bf16x8*)(Bs + (wn * 64 + i * 16 + frow) * BK + fcol);
        }
#pragma unroll
        for (int i = 0; i < 4; ++i)
#pragma unroll
            for (int j = 0; j < 4; ++j)
                acc[i][j] = __builtin_amdgcn_mfma_f32_16x16x32_bf16(
                    af[i], bfr[j], acc[i][j], 0, 0, 0);
        __syncthreads();
    }

    const int crow0 = bm * BM + wm * 64;
    const int ccol0 = bn * BN + wn * 64;
    const int rl = lane >> 4;
    const int cl = lane & 15;
#pragma unroll
    for (int j = 0; j < 4; ++j) {
        const int col = ccol0 + j * 16 + cl;
        const float bv = bias[col];
#pragma unroll
        for (int i = 0; i < 4; ++i) {
            const int row = crow0 + i * 16 + rl * 4;
            float* cp = C + (size_t)row * N_DIM + col;
#pragma unroll
            for (int r = 0; r < 4; ++r)
                cp[(size_t)r * N_DIM] = acc[i][j][r] + bv;
        }
    }
}

// ---------------------------------------------------------------------------
// Kernel 3b (fallback if ws too small): fused fp32-A GEMM with CONFLICT-FREE
// A ds_writes: lane l of wave w writes LDS bytes ((w*64+l)*16) — contiguous
// per wave, banks swept exactly once per 8-lane phase (global_load_lds's
// own pattern). Thread t covers: write1 row t>>2 and write2 row 64+(t>>2),
// k-cols (t&3)*8..+8.
// ---------------------------------------------------------------------------
__global__ void gemm_fused_kernel(const float* __restrict__ X,
                                  const ushort* __restrict__ B,
                                  const float* __restrict__ bias,
                                  float* __restrict__ C) {
    __shared__ ushort As[BM * BK];
    __shared__ ushort Bs[BN * BK];

    const int tid  = threadIdx.x;
    const int lane = tid & 63;
    const int wave = tid >> 6;
    const int wm   = wave >> 1;
    const int wn   = wave & 1;
    const int bm   = blockIdx.y;
    const int bn   = blockIdx.x;

    const int ar = tid >> 2;          // 0..63
    const int ac = (tid & 3) * 8;     // k-offset (elements)
    const float* xp0 = X + (size_t)(bm * BM + ar) * K_DIM + ac;
    const float* xp1 = xp0 + (size_t)64 * K_DIM;
    ushort* as0 = As + ar * BK + ac;
    ushort* as1 = as0 + 64 * BK;

    const int scol = (lane & 3) * 8;
    const ushort* Bb = B + (size_t)(bn * BN) * K_DIM;

    floatx4 acc[4][4] = {};

    for (int k0 = 0; k0 < K_DIM; k0 += BK) {
        float4 a0 = *(const float4*)(xp0 + k0);
        float4 a1 = *(const float4*)(xp0 + k0 + 4);
        float4 b0 = *(const float4*)(xp1 + k0);
        float4 b1 = *(const float4*)(xp1 + k0 + 4);
#pragma unroll
        for (int q = 0; q < 2; ++q) {
            const int chunk = wave * 2 + q;
            const int r = chunk * 16 + (lane >> 2);
            const ushort* gb = Bb + (size_t)r * K_DIM + k0 + scol;
            __builtin_amdgcn_global_load_lds(
                (const __attribute__((address_space(1))) void*)gb,
                (__attribute__((address_space(3))) void*)(Bs + chunk * 512),
                16, 0, 0);
        }
        uint4 w0, w1;
        w0.x = pk_bf_trunc(a0.x, a0.y);
        w0.y = pk_bf_trunc(a0.z, a0.w);
        w0.z = pk_bf_trunc(a1.x, a1.y);
        w0.w = pk_bf_trunc(a1.z, a1.w);
        w1.x = pk_bf_trunc(b0.x, b0.y);
        w1.y = pk_bf_trunc(b0.z, b0.w);
        w1.z = pk_bf_trunc(b1.x, b1.y);
        w1.w = pk_bf_trunc(b1.z, b1.w);
        *(uint4*)as0 = w0;
        *(uint4*)as1 = w1;

        __syncthreads();

        bf16x8 af[4], bfr[4];
        const int frow = lane & 15;
        const int fcol = (lane >> 4) * 8;
#pragma unroll
        for (int i = 0; i < 4; ++i) {
            af[i]  = *(const bf16x8*)(As + (wm * 64 + i * 16 + frow) * BK + fcol);
            bfr[i] = *(const bf16x8*)(Bs + (wn * 64 + i * 16 + frow) * BK + fcol);
        }
#pragma unroll
        for (int i = 0; i < 4; ++i)
#pragma unroll
            for (int j = 0; j < 4; ++j)
                acc[i][j] = __builtin_amdgcn_mfma_f32_16x16x32_bf16(
                    af[i], bfr[j], acc[i][j], 0, 0, 0);
        __syncthreads();
    }

    const int crow0 = bm * BM + wm * 64;
    const int ccol0 = bn * BN + wn * 64;
    const int rl = lane >> 4;
    const int cl = lane & 15;
#pragma unroll
    for (int j = 0; j < 4; ++j) {
        const int col = ccol0 + j * 16 + cl;
        const float bv = bias[col];
#pragma unroll
        for (int i = 0; i < 4; ++i) {
            const int row = crow0 + i * 16 + rl * 4;
            float* cp = C + (size_t)row * N_DIM + col;
#pragma unroll
            for (int r = 0; r < 4; ++r)
                cp[(size_t)r * N_DIM] = acc[i][j][r] + bv;
        }
    }
}

// ---------------------------------------------------------------------------
extern "C" void kernel_launch(void* const* d_in, const int* in_sizes, int n_in,
                              void* d_out, int out_size, void* d_ws, size_t ws_size,
                              hipStream_t stream) {
    const float* x      = (const float*)d_in[0];
    const int*   pw     = (const int*)d_in[1];
    const float* scales = (const float*)d_in[2];
    const float* zps    = (const float*)d_in[3];
    const float* bias   = (const float*)d_in[4];
    float* out = (float*)d_out;

    ushort* wb = (ushort*)d_ws;                        // 33.5 MB

    {
        int np4 = (N_DIM * K_DIM / 2) / 4;
        dequant_w_kernel<<<np4 / 256, 256, 0, stream>>>(
            (const int4*)pw, scales, zps, (uint4*)wb, np4);
    }

    const size_t need = ((size_t)N_DIM * K_DIM + (size_t)CHUNK_M * K_DIM) * 2;
    if (ws_size >= need) {
        // pre-pass path: convert x chunk -> bf16 in ws, run pure-bf16 GEMM
        ushort* xb = wb + (size_t)N_DIM * K_DIM;       // 33.5 MB chunk buffer
        for (int c = 0; c < M_DIM / CHUNK_M; ++c) {
            const float* xc = x + (size_t)c * CHUNK_M * K_DIM;
            float* oc = out + (size_t)c * CHUNK_M * N_DIM;
            int n4 = (CHUNK_M * K_DIM) / 4;
            convert_x_kernel<<<n4 / 256, 256, 0, stream>>>(
                (const float4*)xc, (ushort4*)xb, n4);
            dim3 grid(N_DIM / BN, CHUNK_M / BM);       // (32, 32)
            gemm_bf16_kernel<<<grid, 256, 0, stream>>>(xb, wb, bias, oc);
        }
    } else {
        // fallback: fused conversion with conflict-free LDS writes
        dim3 grid(N_DIM / BN, M_DIM / BM);             // (32, 64)
        gemm_fused_kernel<<<grid, 256, 0, stream>>>(x, wb, bias, out);
    }
}